// Round 17
// baseline (7060.641 us; speedup 1.0000x reference)
//
#include <hip/hip_runtime.h>
#include <stdint.h>

// ---------------------------------------------------------------------------
// Langevin sampler on MFMA. z_{t+1} = 0.92 z + COEF*G + 0.4 n, 60 steps.
//   fwd:  A1 = Z@W1 + b1; H = gelu(A1); A2 = H@W2 + b2        (MFMA)
//   mid:  D2 = W3 .* gelu'(A2)
//   bwd:  A1 recomputed; E = (D2@W2T) .* gelu'(A1)
//   update fused: W1Tp pre-scaled by COEF; zacc pre-loaded with
//   0.92 z + 0.4 n; G-MFMAs accumulate into it -> zacc IS z_{t+1}.
// R17: QUARTER-SPLIT for the 8-wave/SIMD register tier. Cross-round data:
// occupancy drives VALUBusy (22%occ->47-57%, 44%occ->66%); we are pinned at
// 2 blocks/CU because total regs = 64 arch + 24 acc ~= 88 and the HW tier
// boundary is total<=64 (m69). Quarter-split (1024 thr = 16 waves = 4 rg x
// 4 cq): zacc[2]+a2acc[1] = 12 acc, 8 noise draws -> arch target ~52 ->
// total <=64 -> 32 waves/CU (100%). (1024,4): allocator's 2x-min pattern
// gives arch cap 64. Math/RNG/LDS bit-identical to R16 (absmax 0.03125).
// Outcomes: occ 75-95% -> ~4.5ms; occ ~50% -> flat; FETCH>>100MB -> spill,
// revert to R16.
// ---------------------------------------------------------------------------

#define BATCH   65536
#define ZDIM    128
#define H1      512
#define H2      64
#define NSTEP   60
#define COEF    (-0.08f)

using bf16x8 = __attribute__((ext_vector_type(8))) short;
using f32x4  = __attribute__((ext_vector_type(4))) float;

#define MFMA16(a, b, c) __builtin_amdgcn_mfma_f32_16x16x32_bf16((a), (b), (c), 0, 0, 0)

// ----------------------------- threefry2x32 --------------------------------
__device__ __forceinline__ uint32_t rotl32(uint32_t v, int s) {
  return (v << s) | (v >> (32 - s));
}

// scalar 20-round block (per-step fold_in key; wave-uniform -> SALU)
__device__ __forceinline__ void tf2x32(uint32_t k0, uint32_t k1,
                                       uint32_t x0, uint32_t x1,
                                       uint32_t& o0, uint32_t& o1) {
  const uint32_t k2 = k0 ^ k1 ^ 0x1BD11BDAu;
  x0 += k0; x1 += k1;
  x0 += x1; x1 = rotl32(x1, 13); x1 ^= x0;
  x0 += x1; x1 = rotl32(x1, 15); x1 ^= x0;
  x0 += x1; x1 = rotl32(x1, 26); x1 ^= x0;
  x0 += x1; x1 = rotl32(x1,  6); x1 ^= x0;
  x0 += k1; x1 += k2 + 1u;
  x0 += x1; x1 = rotl32(x1, 17); x1 ^= x0;
  x0 += x1; x1 = rotl32(x1, 29); x1 ^= x0;
  x0 += x1; x1 = rotl32(x1, 16); x1 ^= x0;
  x0 += x1; x1 = rotl32(x1, 24); x1 ^= x0;
  x0 += k2; x1 += k0 + 2u;
  x0 += x1; x1 = rotl32(x1, 13); x1 ^= x0;
  x0 += x1; x1 = rotl32(x1, 15); x1 ^= x0;
  x0 += x1; x1 = rotl32(x1, 26); x1 ^= x0;
  x0 += x1; x1 = rotl32(x1,  6); x1 ^= x0;
  x0 += k0; x1 += k1 + 3u;
  x0 += x1; x1 = rotl32(x1, 17); x1 ^= x0;
  x0 += x1; x1 = rotl32(x1, 29); x1 ^= x0;
  x0 += x1; x1 = rotl32(x1, 16); x1 ^= x0;
  x0 += x1; x1 = rotl32(x1, 24); x1 ^= x0;
  x0 += k1; x1 += k2 + 4u;
  x0 += x1; x1 = rotl32(x1, 13); x1 ^= x0;
  x0 += x1; x1 = rotl32(x1, 15); x1 ^= x0;
  x0 += x1; x1 = rotl32(x1, 26); x1 ^= x0;
  x0 += x1; x1 = rotl32(x1,  6); x1 ^= x0;
  x0 += k2; x1 += k0 + 5u;
  o0 = x0; o1 = x1;
}

// --------------- uniform bits -> N(0,1), XLA-compatible --------------------
// w = -ln(1-u^2) via fmaf(-u,u,1) (single-rounded, no cancellation) + __logf.
__device__ __forceinline__ float normal_from_bits(uint32_t bits) {
  float u01 = __uint_as_float((bits >> 9) | 0x3F800000u) - 1.0f;
  const float lo = -0.99999994f;
  float u = fmaxf(lo, u01 * 2.0f + lo);
  float w = -__logf(fmaf(-u, u, 1.0f));
  float p;
  if (w < 5.0f) {
    w -= 2.5f;
    p =             2.81022636e-08f;
    p = fmaf(p, w,  3.43273939e-07f);
    p = fmaf(p, w, -3.5233877e-06f);
    p = fmaf(p, w, -4.39150654e-06f);
    p = fmaf(p, w,  0.00021858087f);
    p = fmaf(p, w, -0.00125372503f);
    p = fmaf(p, w, -0.00417768164f);
    p = fmaf(p, w,  0.246640727f);
    p = fmaf(p, w,  1.50140941f);
  } else {
    w = sqrtf(w) - 3.0f;
    p =            -0.000200214257f;
    p = fmaf(p, w,  0.000100950558f);
    p = fmaf(p, w,  0.00134934322f);
    p = fmaf(p, w, -0.00367342844f);
    p = fmaf(p, w,  0.00573950773f);
    p = fmaf(p, w, -0.0076224613f);
    p = fmaf(p, w,  0.00943887047f);
    p = fmaf(p, w,  1.00167406f);
    p = fmaf(p, w,  2.83297682f);
  }
  return 1.41421356f * (p * u);
}

// 4 independent threefry draws (flat indices f0 + {0,128,256,384} = 4 rows).
struct N4 { float v[4]; };
__device__ __forceinline__ N4 noise4(uint32_t k0, uint32_t k1, uint32_t f0) {
  const uint32_t k2 = k0 ^ k1 ^ 0x1BD11BDAu;
  uint32_t x0[4], x1[4];
  #pragma unroll
  for (int i = 0; i < 4; ++i) { x0[i] = k0; x1[i] = (f0 + 128u * (uint32_t)i) + k1; }
#define TFG(ra, rb, rc, rd, ia, ib, ic)                                        \
  _Pragma("unroll")                                                            \
  for (int i = 0; i < 4; ++i) {                                                \
    x0[i] += x1[i]; x1[i] = rotl32(x1[i], ra); x1[i] ^= x0[i];                 \
    x0[i] += x1[i]; x1[i] = rotl32(x1[i], rb); x1[i] ^= x0[i];                 \
    x0[i] += x1[i]; x1[i] = rotl32(x1[i], rc); x1[i] ^= x0[i];                 \
    x0[i] += x1[i]; x1[i] = rotl32(x1[i], rd); x1[i] ^= x0[i];                 \
    x0[i] += (ia); x1[i] += (ib) + (ic); }
  TFG(13, 15, 26,  6, k1, k2, 1u)
  TFG(17, 29, 16, 24, k2, k0, 2u)
  TFG(13, 15, 26,  6, k0, k1, 3u)
  TFG(17, 29, 16, 24, k1, k2, 4u)
  TFG(13, 15, 26,  6, k2, k0, 5u)
#undef TFG
  N4 r;
  #pragma unroll
  for (int i = 0; i < 4; ++i) r.v[i] = normal_from_bits(x0[i] ^ x1[i]);
  return r;
}

// ------------------------------ fast GELU -----------------------------------
__device__ __forceinline__ float sigm(float y) {
  return __fdividef(1.0f, 1.0f + __expf(-y));
}
__device__ __forceinline__ float gelu_fast(float x) { return x * sigm(1.702f * x); }
__device__ __forceinline__ float gelu_grad_fast(float x) {
  float s = sigm(1.702f * x);
  return fmaf(1.702f * x, s * (1.0f - s), s);
}

// exact GELU (scalar fallback path)
__device__ __forceinline__ float gelu_exact(float x) {
  return 0.5f * x * (1.0f + erff(x * 0.70710678f));
}
__device__ __forceinline__ float gelu_grad_exact(float x) {
  float u   = x * 0.70710678f;
  float cdf = 0.5f * (1.0f + erff(u));
  float pdf = 0.39894228040143267f * expf(-u * u);
  return fmaf(x, pdf, cdf);
}

__device__ __forceinline__ unsigned short f2bf(float x) {
  return (unsigned short)(__float_as_uint(x) >> 16);
}

// ------------------------- weight packing (B-frags) -------------------------
// Pack scale*M [K x N] (M = src, or src^T if trans) into MFMA-B tiles:
// tile t = kb*(N/16)+cb; lane l, elem j -> M[kb*32+(l>>4)*8+j][cb*16+(l&15)].
__global__ void pack_b(const float* __restrict__ src, unsigned short* __restrict__ dst,
                       int K, int N, int trans, int total, float scale) {
  int o = blockIdx.x * 256 + threadIdx.x;
  if (o >= total) return;
  int t   = o >> 9;
  int rem = o & 511;
  int l = rem >> 3, j = rem & 7;
  int nb = N >> 4;
  int kb = t / nb, cb = t - kb * nb;
  int k = kb * 32 + (l >> 4) * 8 + j;
  int n = cb * 16 + (l & 15);
  float v = trans ? src[(size_t)n * K + k] : src[(size_t)k * N + n];
  dst[o] = f2bf(scale * v);
}

// LDS A-frag read with XOR swizzle; conflict-free ds_read_b128 (§6 G4).
__device__ __forceinline__ bf16x8 lds_frag(const unsigned short* lds, int row,
                                           int ebase, int rowElems) {
  int e = ebase ^ ((row & 7) << 3);
  return *(const bf16x8*)(lds + row * rowElems + e);
}
__device__ __forceinline__ bf16x8 load_frag(const unsigned short* p, int tile, int lane) {
  return *(const bf16x8*)(p + tile * 512 + lane * 8);
}

// ------------------------------- main kernel --------------------------------
// 1024 threads = 16 waves: wave wid -> (rg = wid>>2 row-group, cq = wid&3
// col-quarter). Per-thread: zacc[2] (cols cq*32..+31), a2acc[1], 8 draws.
// (1024,4): arch cap 64 (2x-min allocator pattern); target total<=64 ->
// 8 waves/SIMD tier -> 2 blocks/CU (32 waves, 100%).
__global__ __launch_bounds__(1024, 4) void langevin_mfma(
    const float* __restrict__ z0,
    const float* __restrict__ b1,
    const float* __restrict__ b2,
    const float* __restrict__ W3,
    const unsigned short* __restrict__ W1p,    // [128x512] B-tiles (128)
    const unsigned short* __restrict__ W2p,    // [512x64]  B-tiles (64)
    const unsigned short* __restrict__ W2Tp,   // [64x512]  B-tiles (64)
    const unsigned short* __restrict__ W1Tp,   // [512x128] B-tiles (256), COEF-scaled
    float* __restrict__ out)
{
  __shared__ unsigned short Zlds[64 * 128];   // 16KB
  __shared__ unsigned short HEu[64 * 64];     //  8KB: H (fwd) / E (bwd) union
  __shared__ unsigned short D2lds[64 * 64];   //  8KB
  __shared__ float b1lds[512];
  __shared__ float b2lds[64];
  __shared__ float w3lds[64];

  const int tid  = threadIdx.x;
  const int lane = tid & 63;
  const int wid  = tid >> 6;            // 0..15
  const int rg   = wid >> 2;            // row-group 0..3 (16 rows)
  const int cq   = wid & 3;             // col-quarter 0..3
  const int wg   = blockIdx.x;

  if (tid < 512) b1lds[tid] = b1[tid];
  if (tid < 64) { b2lds[tid] = b2[tid]; w3lds[tid] = W3[tid]; }

  const int rbase = rg * 16 + ((lane >> 4) << 2);  // D-layout row (i adds 0..3)
  const int clane = lane & 15;
  const int arow  = rg * 16 + clane;               // A-frag row
  const int ahi   = (lane >> 4) << 3;              // A-frag k-subblock

  // ---- init: zacc = 2 t-tiles (t = cq*2+tl) of f32 z; Zlds bf16 copy ----
  f32x4 zacc[2];
  #pragma unroll
  for (int tl = 0; tl < 2; ++tl) {
    const int t = cq * 2 + tl;
    #pragma unroll
    for (int i = 0; i < 4; ++i) {
      int row = rbase + i;
      int col = t * 16 + clane;
      float zv = z0[(size_t)(wg * 64 + row) * ZDIM + col];
      zacc[tl][i] = zv;
      Zlds[row * 128 + (col ^ ((row & 7) << 3))] = f2bf(zv);
    }
  }

  for (int step = 0; step < NSTEP; ++step) {
    uint32_t fk0, fk1;
    tf2x32(0u, 42u, 0u, (uint32_t)step, fk0, fk1);

    // ---------------- forward ----------------
    f32x4 a2acc;
    {
      float bb = b2lds[cq * 16 + clane];
      a2acc = f32x4{bb, bb, bb, bb};
    }

    #pragma unroll 1
    for (int jb = 0; jb < 8; ++jb) {
      __syncthreads();   // Zlds/HEu stable; waves lockstep for L1 frag reuse
      {
        // this wave's col-tile of the jb block: ct = cq
        f32x4 acc = f32x4{0.f, 0.f, 0.f, 0.f};
        #pragma unroll
        for (int kb = 0; kb < 4; ++kb) {
          bf16x8 za = lds_frag(Zlds, arow, kb * 32 + ahi, 128);
          acc = MFMA16(za, load_frag(W1p, kb * 32 + jb * 4 + cq, lane), acc);
        }
        float bb = b1lds[jb * 64 + cq * 16 + clane];
        #pragma unroll
        for (int i = 0; i < 4; ++i) {
          int row = rbase + i;
          int c   = cq * 16 + clane;
          HEu[row * 64 + (c ^ ((row & 7) << 3))] = f2bf(gelu_fast(acc[i] + bb));
        }
      }
      __syncthreads();   // H complete (all col-quarters) before K-dim read
      #pragma unroll
      for (int kb = 0; kb < 2; ++kb) {
        bf16x8 ha = lds_frag(HEu, arow, kb * 32 + ahi, 64);
        a2acc = MFMA16(ha, load_frag(W2p, (jb * 2 + kb) * 4 + cq, lane), a2acc);
      }
    }

    // ---------------- D2 = W3 .* gelu'(A2) ----------------
    {
      float w3v = w3lds[cq * 16 + clane];
      #pragma unroll
      for (int i = 0; i < 4; ++i) {
        int row = rbase + i;
        int c   = cq * 16 + clane;
        D2lds[row * 64 + (c ^ ((row & 7) << 3))] = f2bf(w3v * gelu_grad_fast(a2acc[i]));
      }
    }

    // ---------------- noise + z pre-update (zacc <- 0.92 z + 0.4 n) --------
    {
      const uint32_t gs0 = (uint32_t)(wg * 64 + rbase) * 128u;
      #pragma unroll
      for (int tl = 0; tl < 2; ++tl) {
        N4 nz = noise4(fk0, fk1, gs0 + (uint32_t)((cq * 2 + tl) * 16 + clane));
        #pragma unroll
        for (int i = 0; i < 4; ++i) {
          float zv = zacc[tl][i];
          zacc[tl][i] = fmaf(0.4f, nz.v[i], fmaf(COEF, zv, zv));
        }
        __builtin_amdgcn_sched_barrier(0);
      }
    }

    // ---------------- backward: zacc += E @ (COEF*W1T) ----------------
    #pragma unroll 1
    for (int jb = 0; jb < 8; ++jb) {
      __syncthreads();   // D2 complete (jb=0) / HEu reads of jb-1 done
      bf16x8 d2a0 = lds_frag(D2lds, arow, 0  + ahi, 64);
      bf16x8 d2a1 = lds_frag(D2lds, arow, 32 + ahi, 64);
      {
        // E col-tile ct = cq of the jb block
        f32x4 eacc = f32x4{0.f, 0.f, 0.f, 0.f};
        eacc = MFMA16(d2a0, load_frag(W2Tp,      jb * 4 + cq, lane), eacc);
        eacc = MFMA16(d2a1, load_frag(W2Tp, 32 + jb * 4 + cq, lane), eacc);
        f32x4 a1acc = f32x4{0.f, 0.f, 0.f, 0.f};
        #pragma unroll
        for (int kb = 0; kb < 4; ++kb) {
          bf16x8 za = lds_frag(Zlds, arow, kb * 32 + ahi, 128);
          a1acc = MFMA16(za, load_frag(W1p, kb * 32 + jb * 4 + cq, lane), a1acc);
        }
        float bb = b1lds[jb * 64 + cq * 16 + clane];
        #pragma unroll
        for (int i = 0; i < 4; ++i) {
          int row = rbase + i;
          int c   = cq * 16 + clane;
          float ev = eacc[i] * gelu_grad_fast(a1acc[i] + bb);
          HEu[row * 64 + (c ^ ((row & 7) << 3))] = f2bf(ev);
        }
      }
      __syncthreads();   // E complete (all col-quarters) before K-dim read
      #pragma unroll
      for (int kb = 0; kb < 2; ++kb) {
        bf16x8 ea = lds_frag(HEu, arow, kb * 32 + ahi, 64);
        #pragma unroll
        for (int tl = 0; tl < 2; ++tl)
          zacc[tl] = MFMA16(ea, load_frag(W1Tp, (jb * 2 + kb) * 8 + cq * 2 + tl, lane),
                            zacc[tl]);
      }
    }

    // ---------------- Zlds refresh with z_{t+1} ----------------
    // Safe: all Zlds reads of this step happened before the jb=7 mid-barrier.
    #pragma unroll
    for (int tl = 0; tl < 2; ++tl) {
      const int t = cq * 2 + tl;
      #pragma unroll
      for (int i = 0; i < 4; ++i) {
        int row = rbase + i;
        int col = t * 16 + clane;
        Zlds[row * 128 + (col ^ ((row & 7) << 3))] = f2bf(zacc[tl][i]);
      }
    }
    // next step's fwd jb=0 top barrier makes the refresh visible.
  }

  // ---- store ----
  #pragma unroll
  for (int tl = 0; tl < 2; ++tl) {
    const int t = cq * 2 + tl;
    #pragma unroll
    for (int i = 0; i < 4; ++i) {
      int row = rbase + i;
      out[(size_t)(wg * 64 + row) * ZDIM + t * 16 + clane] = zacc[tl][i];
    }
  }
}

// ===================== scalar fallback (round-3, verified) ==================
__global__ void transpose_w1(const float* __restrict__ W1, float* __restrict__ W1T) {
  int o = blockIdx.x * 256 + threadIdx.x;
  int j = o >> 7, k = o & 127;
  W1T[o] = W1[k * H1 + j];
}

__device__ __forceinline__ float normal_from_bits_exact(uint32_t bits) {
  float u01 = __uint_as_float((bits >> 9) | 0x3F800000u) - 1.0f;
  const float lo = -0.99999994f;
  float u = fmaxf(lo, u01 * 2.0f + lo);
  float w = -log1pf(-u * u);
  float p;
  if (w < 5.0f) {
    w -= 2.5f;
    p =             2.81022636e-08f;
    p = fmaf(p, w,  3.43273939e-07f);
    p = fmaf(p, w, -3.5233877e-06f);
    p = fmaf(p, w, -4.39150654e-06f);
    p = fmaf(p, w,  0.00021858087f);
    p = fmaf(p, w, -0.00125372503f);
    p = fmaf(p, w, -0.00417768164f);
    p = fmaf(p, w,  0.246640727f);
    p = fmaf(p, w,  1.50140941f);
  } else {
    w = sqrtf(w) - 3.0f;
    p =            -0.000200214257f;
    p = fmaf(p, w,  0.000100950558f);
    p = fmaf(p, w,  0.00134934322f);
    p = fmaf(p, w, -0.00367342844f);
    p = fmaf(p, w,  0.00573950773f);
    p = fmaf(p, w, -0.0076224613f);
    p = fmaf(p, w,  0.00943887047f);
    p = fmaf(p, w,  1.00167406f);
    p = fmaf(p, w,  2.83297682f);
  }
  return 1.41421356f * (p * u);
}

__global__ __launch_bounds__(256, 1) void langevin_scalar(
    const float* __restrict__ z0, const float* __restrict__ b1,
    const float* __restrict__ W2, const float* __restrict__ b2,
    const float* __restrict__ W3, const float* __restrict__ W1T,
    float* __restrict__ out)
{
  __shared__ float nbuf[256 * 33];
  const int tid = threadIdx.x;
  const uint32_t b = (uint32_t)blockIdx.x * 256u + (uint32_t)tid;
  float z[ZDIM];
  #pragma unroll
  for (int k = 0; k < ZDIM; ++k) z[k] = z0[(size_t)b * ZDIM + k];
  for (int step = 0; step < NSTEP; ++step) {
    uint32_t fk0, fk1;
    tf2x32(0u, 42u, 0u, (uint32_t)step, fk0, fk1);
    float acc2[H2];
    #pragma unroll
    for (int c = 0; c < H2; ++c) acc2[c] = b2[c];
    #pragma unroll 2
    for (int j = 0; j < H1; ++j) {
      const float* __restrict__ w = W1T + j * ZDIM;
      float s0 = 0.f, s1 = 0.f, s2 = 0.f, s3 = 0.f;
      #pragma unroll
      for (int k = 0; k < ZDIM; k += 4) {
        s0 = fmaf(z[k + 0], w[k + 0], s0); s1 = fmaf(z[k + 1], w[k + 1], s1);
        s2 = fmaf(z[k + 2], w[k + 2], s2); s3 = fmaf(z[k + 3], w[k + 3], s3);
      }
      float a1 = b1[j] + ((s0 + s1) + (s2 + s3));
      float h  = gelu_exact(a1);
      const float* __restrict__ w2r = W2 + j * H2;
      #pragma unroll
      for (int c = 0; c < H2; ++c) acc2[c] = fmaf(h, w2r[c], acc2[c]);
    }
    #pragma unroll
    for (int c = 0; c < H2; ++c) acc2[c] = W3[c] * gelu_grad_exact(acc2[c]);
    float g[ZDIM];
    #pragma unroll
    for (int k = 0; k < ZDIM; ++k) g[k] = 0.f;
    for (int j = 0; j < H1; ++j) {
      const float* __restrict__ w = W1T + j * ZDIM;
      float s0 = 0.f, s1 = 0.f, s2 = 0.f, s3 = 0.f;
      #pragma unroll
      for (int k = 0; k < ZDIM; k += 4) {
        s0 = fmaf(z[k + 0], w[k + 0], s0); s1 = fmaf(z[k + 1], w[k + 1], s1);
        s2 = fmaf(z[k + 2], w[k + 2], s2); s3 = fmaf(z[k + 3], w[k + 3], s3);
      }
      float a1 = b1[j] + ((s0 + s1) + (s2 + s3));
      const float* __restrict__ w2r = W2 + j * H2;
      float d0 = 0.f, d1 = 0.f, d2 = 0.f, d3 = 0.f;
      #pragma unroll
      for (int c = 0; c < H2; c += 4) {
        d0 = fmaf(acc2[c + 0], w2r[c + 0], d0); d1 = fmaf(acc2[c + 1], w2r[c + 1], d1);
        d2 = fmaf(acc2[c + 2], w2r[c + 2], d2); d3 = fmaf(acc2[c + 3], w2r[c + 3], d3);
      }
      float eps = ((d0 + d1) + (d2 + d3)) * gelu_grad_exact(a1);
      #pragma unroll
      for (int k = 0; k < ZDIM; ++k) g[k] = fmaf(eps, w[k], g[k]);
    }
    const uint32_t base = b * (uint32_t)ZDIM;
    #pragma unroll
    for (int kc = 0; kc < 4; ++kc) {
      for (int kk = 0; kk < 32; ++kk) {
        uint32_t f = base + (uint32_t)(kc * 32 + kk);
        uint32_t r0, r1;
        tf2x32(fk0, fk1, 0u, f, r0, r1);
        nbuf[tid * 33 + kk] = normal_from_bits_exact(r0 ^ r1);
      }
      #pragma unroll
      for (int i = 0; i < 32; ++i) {
        const int k = kc * 32 + i;
        z[k] += COEF * g[k] + COEF * z[k] + 0.4f * nbuf[tid * 33 + i];
      }
    }
  }
  #pragma unroll
  for (int k = 0; k < ZDIM; ++k) out[(size_t)b * ZDIM + k] = z[k];
}

// ------------------------------- launcher ----------------------------------
extern "C" void kernel_launch(void* const* d_in, const int* in_sizes, int n_in,
                              void* d_out, int out_size, void* d_ws, size_t ws_size,
                              hipStream_t stream) {
  (void)in_sizes; (void)n_in; (void)out_size;

  const float* z0 = (const float*)d_in[0];
  const float* W1 = (const float*)d_in[1];
  const float* b1 = (const float*)d_in[2];
  const float* W2 = (const float*)d_in[3];
  const float* b2 = (const float*)d_in[4];
  const float* W3 = (const float*)d_in[5];
  float* out = (float*)d_out;

  const size_t NEED = 196608u * 2u;   // 384 KB of packed bf16 tiles
  if (ws_size >= NEED) {
    unsigned short* W1p  = (unsigned short*)d_ws;
    unsigned short* W2p  = W1p  + 65536;
    unsigned short* W2Tp = W2p  + 32768;
    unsigned short* W1Tp = W2Tp + 32768;

    hipLaunchKernelGGL(pack_b, dim3(256), dim3(256), 0, stream, W1, W1p,  128, 512, 0, 65536, 1.0f);
    hipLaunchKernelGGL(pack_b, dim3(128), dim3(256), 0, stream, W2, W2p,  512,  64, 0, 32768, 1.0f);
    hipLaunchKernelGGL(pack_b, dim3(128), dim3(256), 0, stream, W2, W2Tp,  64, 512, 1, 32768, 1.0f);
    // W1Tp PRE-SCALED by COEF: bwd MFMAs accumulate COEF*G directly into zacc.
    hipLaunchKernelGGL(pack_b, dim3(256), dim3(256), 0, stream, W1, W1Tp, 512, 128, 1, 65536, COEF);
    hipLaunchKernelGGL(langevin_mfma, dim3(BATCH / 64), dim3(1024), 0, stream,
                       z0, b1, b2, W3, W1p, W2p, W2Tp, W1Tp, out);
  } else {
    float* W1T = (float*)d_ws;
    hipLaunchKernelGGL(transpose_w1, dim3(256), dim3(256), 0, stream, W1, W1T);
    hipLaunchKernelGGL(langevin_scalar, dim3(BATCH / 256), dim3(256), 0, stream,
                       z0, b1, W2, b2, W3, W1T, out);
  }
}

// Round 18
// 5777.106 us; speedup vs baseline: 1.2222x; 1.2222x over previous
//
#include <hip/hip_runtime.h>
#include <stdint.h>

// ---------------------------------------------------------------------------
// Langevin sampler on MFMA. z_{t+1} = 0.92 z + COEF*G + 0.4 n, 60 steps.
//   fwd:  A1 = Z@W1 + b1; H = gelu(A1); A2 = H@W2 + b2        (MFMA)
//   mid:  D2 = W3 .* gelu'(A2)
//   bwd:  A1 recomputed; E = (D2@W2T) .* gelu'(A1)
//   update fused: W1Tp pre-scaled by COEF; zacc pre-loaded with
//   0.92 z + 0.4 n; G-MFMAs accumulate into it -> zacc IS z_{t+1}.
// FINAL = R10/R16 configuration (best measured: 5784/5793 us, verified 2x).
// Complete hypothesis ledger (all counter-verified):
//   R5-R7  occupancy tiers: launch_bounds min>=3 makes allocator overshoot
//          (VGPR 84/64 + spill); min=2 is the sane point.
//   R10    column-split 512thr: spill eliminated (FETCH 1.7GB -> 27MB). WIN.
//   R11    readfirstlane scalarization: null (addressing wasn't the gap).
//   R12    barrier halving + lgkm-only barriers: null (barriers weren't it).
//   R14/15 dg-cache work deletion: algorithmically correct but needs +32
//          VGPR; no spill-free tier has them. A1-recompute on the 87%-idle
//          MFMA pipe is cheaper. REVERTED.
//   R17    quarter-split 1024thr: total 68 regs, 3 over the <=64 tier ->
//          50% occ + doubled bank conflicts -> 22% regression. REVERTED.
// Floor: ~4.5ms VALU instruction stream (threefry+staging+transcendentals)
// + ~20% issue bubbles. 12.9x over scalar baseline; RNG bit-faithful.
// ---------------------------------------------------------------------------

#define BATCH   65536
#define ZDIM    128
#define H1      512
#define H2      64
#define NSTEP   60
#define COEF    (-0.08f)

using bf16x8 = __attribute__((ext_vector_type(8))) short;
using f32x4  = __attribute__((ext_vector_type(4))) float;

#define MFMA16(a, b, c) __builtin_amdgcn_mfma_f32_16x16x32_bf16((a), (b), (c), 0, 0, 0)

// ----------------------------- threefry2x32 --------------------------------
__device__ __forceinline__ uint32_t rotl32(uint32_t v, int s) {
  return (v << s) | (v >> (32 - s));
}

// scalar 20-round block (per-step fold_in key; wave-uniform -> SALU)
__device__ __forceinline__ void tf2x32(uint32_t k0, uint32_t k1,
                                       uint32_t x0, uint32_t x1,
                                       uint32_t& o0, uint32_t& o1) {
  const uint32_t k2 = k0 ^ k1 ^ 0x1BD11BDAu;
  x0 += k0; x1 += k1;
  x0 += x1; x1 = rotl32(x1, 13); x1 ^= x0;
  x0 += x1; x1 = rotl32(x1, 15); x1 ^= x0;
  x0 += x1; x1 = rotl32(x1, 26); x1 ^= x0;
  x0 += x1; x1 = rotl32(x1,  6); x1 ^= x0;
  x0 += k1; x1 += k2 + 1u;
  x0 += x1; x1 = rotl32(x1, 17); x1 ^= x0;
  x0 += x1; x1 = rotl32(x1, 29); x1 ^= x0;
  x0 += x1; x1 = rotl32(x1, 16); x1 ^= x0;
  x0 += x1; x1 = rotl32(x1, 24); x1 ^= x0;
  x0 += k2; x1 += k0 + 2u;
  x0 += x1; x1 = rotl32(x1, 13); x1 ^= x0;
  x0 += x1; x1 = rotl32(x1, 15); x1 ^= x0;
  x0 += x1; x1 = rotl32(x1, 26); x1 ^= x0;
  x0 += x1; x1 = rotl32(x1,  6); x1 ^= x0;
  x0 += k0; x1 += k1 + 3u;
  x0 += x1; x1 = rotl32(x1, 17); x1 ^= x0;
  x0 += x1; x1 = rotl32(x1, 29); x1 ^= x0;
  x0 += x1; x1 = rotl32(x1, 16); x1 ^= x0;
  x0 += x1; x1 = rotl32(x1, 24); x1 ^= x0;
  x0 += k1; x1 += k2 + 4u;
  x0 += x1; x1 = rotl32(x1, 13); x1 ^= x0;
  x0 += x1; x1 = rotl32(x1, 15); x1 ^= x0;
  x0 += x1; x1 = rotl32(x1, 26); x1 ^= x0;
  x0 += x1; x1 = rotl32(x1,  6); x1 ^= x0;
  x0 += k2; x1 += k0 + 5u;
  o0 = x0; o1 = x1;
}

// --------------- uniform bits -> N(0,1), XLA-compatible --------------------
// w = -ln(1-u^2) via fmaf(-u,u,1) (single-rounded, no cancellation) + __logf.
__device__ __forceinline__ float normal_from_bits(uint32_t bits) {
  float u01 = __uint_as_float((bits >> 9) | 0x3F800000u) - 1.0f;
  const float lo = -0.99999994f;
  float u = fmaxf(lo, u01 * 2.0f + lo);
  float w = -__logf(fmaf(-u, u, 1.0f));
  float p;
  if (w < 5.0f) {
    w -= 2.5f;
    p =             2.81022636e-08f;
    p = fmaf(p, w,  3.43273939e-07f);
    p = fmaf(p, w, -3.5233877e-06f);
    p = fmaf(p, w, -4.39150654e-06f);
    p = fmaf(p, w,  0.00021858087f);
    p = fmaf(p, w, -0.00125372503f);
    p = fmaf(p, w, -0.00417768164f);
    p = fmaf(p, w,  0.246640727f);
    p = fmaf(p, w,  1.50140941f);
  } else {
    w = sqrtf(w) - 3.0f;
    p =            -0.000200214257f;
    p = fmaf(p, w,  0.000100950558f);
    p = fmaf(p, w,  0.00134934322f);
    p = fmaf(p, w, -0.00367342844f);
    p = fmaf(p, w,  0.00573950773f);
    p = fmaf(p, w, -0.0076224613f);
    p = fmaf(p, w,  0.00943887047f);
    p = fmaf(p, w,  1.00167406f);
    p = fmaf(p, w,  2.83297682f);
  }
  return 1.41421356f * (p * u);
}

// 4 independent threefry draws (flat indices f0 + {0,128,256,384} = 4 rows).
struct N4 { float v[4]; };
__device__ __forceinline__ N4 noise4(uint32_t k0, uint32_t k1, uint32_t f0) {
  const uint32_t k2 = k0 ^ k1 ^ 0x1BD11BDAu;
  uint32_t x0[4], x1[4];
  #pragma unroll
  for (int i = 0; i < 4; ++i) { x0[i] = k0; x1[i] = (f0 + 128u * (uint32_t)i) + k1; }
#define TFG(ra, rb, rc, rd, ia, ib, ic)                                        \
  _Pragma("unroll")                                                            \
  for (int i = 0; i < 4; ++i) {                                                \
    x0[i] += x1[i]; x1[i] = rotl32(x1[i], ra); x1[i] ^= x0[i];                 \
    x0[i] += x1[i]; x1[i] = rotl32(x1[i], rb); x1[i] ^= x0[i];                 \
    x0[i] += x1[i]; x1[i] = rotl32(x1[i], rc); x1[i] ^= x0[i];                 \
    x0[i] += x1[i]; x1[i] = rotl32(x1[i], rd); x1[i] ^= x0[i];                 \
    x0[i] += (ia); x1[i] += (ib) + (ic); }
  TFG(13, 15, 26,  6, k1, k2, 1u)
  TFG(17, 29, 16, 24, k2, k0, 2u)
  TFG(13, 15, 26,  6, k0, k1, 3u)
  TFG(17, 29, 16, 24, k1, k2, 4u)
  TFG(13, 15, 26,  6, k2, k0, 5u)
#undef TFG
  N4 r;
  #pragma unroll
  for (int i = 0; i < 4; ++i) r.v[i] = normal_from_bits(x0[i] ^ x1[i]);
  return r;
}

// ------------------------------ fast GELU -----------------------------------
__device__ __forceinline__ float sigm(float y) {
  return __fdividef(1.0f, 1.0f + __expf(-y));
}
__device__ __forceinline__ float gelu_fast(float x) { return x * sigm(1.702f * x); }
__device__ __forceinline__ float gelu_grad_fast(float x) {
  float s = sigm(1.702f * x);
  return fmaf(1.702f * x, s * (1.0f - s), s);
}

// exact GELU (scalar fallback path)
__device__ __forceinline__ float gelu_exact(float x) {
  return 0.5f * x * (1.0f + erff(x * 0.70710678f));
}
__device__ __forceinline__ float gelu_grad_exact(float x) {
  float u   = x * 0.70710678f;
  float cdf = 0.5f * (1.0f + erff(u));
  float pdf = 0.39894228040143267f * expf(-u * u);
  return fmaf(x, pdf, cdf);
}

__device__ __forceinline__ unsigned short f2bf(float x) {
  return (unsigned short)(__float_as_uint(x) >> 16);
}

// ------------------------- weight packing (B-frags) -------------------------
// Pack scale*M [K x N] (M = src, or src^T if trans) into MFMA-B tiles:
// tile t = kb*(N/16)+cb; lane l, elem j -> M[kb*32+(l>>4)*8+j][cb*16+(l&15)].
__global__ void pack_b(const float* __restrict__ src, unsigned short* __restrict__ dst,
                       int K, int N, int trans, int total, float scale) {
  int o = blockIdx.x * 256 + threadIdx.x;
  if (o >= total) return;
  int t   = o >> 9;
  int rem = o & 511;
  int l = rem >> 3, j = rem & 7;
  int nb = N >> 4;
  int kb = t / nb, cb = t - kb * nb;
  int k = kb * 32 + (l >> 4) * 8 + j;
  int n = cb * 16 + (l & 15);
  float v = trans ? src[(size_t)n * K + k] : src[(size_t)k * N + n];
  dst[o] = f2bf(scale * v);
}

// LDS A-frag read with XOR swizzle; conflict-free ds_read_b128 (§6 G4).
__device__ __forceinline__ bf16x8 lds_frag(const unsigned short* lds, int row,
                                           int ebase, int rowElems) {
  int e = ebase ^ ((row & 7) << 3);
  return *(const bf16x8*)(lds + row * rowElems + e);
}
__device__ __forceinline__ bf16x8 load_frag(const unsigned short* p, int tile, int lane) {
  return *(const bf16x8*)(p + tile * 512 + lane * 8);
}

// ------------------------------- main kernel --------------------------------
// 512 threads = 8 waves: wave wid -> (rg = wid>>1 row-group, ch = wid&1
// col-half). Per-thread: zacc[4] (cols ch*64..+63), a2acc[2], 16 noise draws.
// (512,4): 2 blocks/CU (16 waves/CU), VGPR 64, spill-free (R10/R16-measured).
__global__ __launch_bounds__(512, 4) void langevin_mfma(
    const float* __restrict__ z0,
    const float* __restrict__ b1,
    const float* __restrict__ b2,
    const float* __restrict__ W3,
    const unsigned short* __restrict__ W1p,    // [128x512] B-tiles (128)
    const unsigned short* __restrict__ W2p,    // [512x64]  B-tiles (64)
    const unsigned short* __restrict__ W2Tp,   // [64x512]  B-tiles (64)
    const unsigned short* __restrict__ W1Tp,   // [512x128] B-tiles (256), COEF-scaled
    float* __restrict__ out)
{
  __shared__ unsigned short Zlds[64 * 128];   // 16KB
  __shared__ unsigned short HEu[64 * 64];     //  8KB: H (fwd) / E (bwd) union
  __shared__ unsigned short D2lds[64 * 64];   //  8KB
  __shared__ float b1lds[512];
  __shared__ float b2lds[64];
  __shared__ float w3lds[64];

  const int tid  = threadIdx.x;
  const int lane = tid & 63;
  const int wid  = tid >> 6;            // 0..7
  const int rg   = wid >> 1;            // row-group 0..3 (16 rows)
  const int ch   = wid & 1;             // col-half 0..1
  const int wg   = blockIdx.x;

  b1lds[tid] = b1[tid];                 // 512 threads cover 512 entries
  if (tid < 64) { b2lds[tid] = b2[tid]; w3lds[tid] = W3[tid]; }

  const int rbase = rg * 16 + ((lane >> 4) << 2);  // D-layout row (i adds 0..3)
  const int clane = lane & 15;
  const int arow  = rg * 16 + clane;               // A-frag row
  const int ahi   = (lane >> 4) << 3;              // A-frag k-subblock

  // ---- init: zacc = 4 t-tiles (t = ch*4+tl) of f32 z; Zlds bf16 copy ----
  f32x4 zacc[4];
  #pragma unroll
  for (int tl = 0; tl < 4; ++tl) {
    const int t = ch * 4 + tl;
    #pragma unroll
    for (int i = 0; i < 4; ++i) {
      int row = rbase + i;
      int col = t * 16 + clane;
      float zv = z0[(size_t)(wg * 64 + row) * ZDIM + col];
      zacc[tl][i] = zv;
      Zlds[row * 128 + (col ^ ((row & 7) << 3))] = f2bf(zv);
    }
  }

  for (int step = 0; step < NSTEP; ++step) {
    uint32_t fk0, fk1;
    tf2x32(0u, 42u, 0u, (uint32_t)step, fk0, fk1);

    // ---------------- forward ----------------
    f32x4 a2acc[2];
    #pragma unroll
    for (int ctl = 0; ctl < 2; ++ctl) {
      float bb = b2lds[(ch * 2 + ctl) * 16 + clane];
      a2acc[ctl] = f32x4{bb, bb, bb, bb};
    }

    #pragma unroll 1
    for (int jb = 0; jb < 8; ++jb) {
      __syncthreads();   // Zlds/HEu stable; waves lockstep for L1 frag reuse
      #pragma unroll
      for (int ctl = 0; ctl < 2; ++ctl) {
        const int ct = ch * 2 + ctl;
        f32x4 acc = f32x4{0.f, 0.f, 0.f, 0.f};
        #pragma unroll
        for (int kb = 0; kb < 4; ++kb) {
          bf16x8 za = lds_frag(Zlds, arow, kb * 32 + ahi, 128);
          acc = MFMA16(za, load_frag(W1p, kb * 32 + jb * 4 + ct, lane), acc);
        }
        float bb = b1lds[jb * 64 + ct * 16 + clane];
        #pragma unroll
        for (int i = 0; i < 4; ++i) {
          int row = rbase + i;
          int c   = ct * 16 + clane;
          HEu[row * 64 + (c ^ ((row & 7) << 3))] = f2bf(gelu_fast(acc[i] + bb));
        }
      }
      __syncthreads();   // H complete (both col-halves) before K-dim read
      #pragma unroll
      for (int kb = 0; kb < 2; ++kb) {
        bf16x8 ha = lds_frag(HEu, arow, kb * 32 + ahi, 64);
        #pragma unroll
        for (int ctl = 0; ctl < 2; ++ctl)
          a2acc[ctl] = MFMA16(ha, load_frag(W2p, (jb * 2 + kb) * 4 + ch * 2 + ctl, lane),
                              a2acc[ctl]);
      }
    }

    // ---------------- D2 = W3 .* gelu'(A2) ----------------
    #pragma unroll
    for (int ctl = 0; ctl < 2; ++ctl) {
      const int ct = ch * 2 + ctl;
      float w3v = w3lds[ct * 16 + clane];
      #pragma unroll
      for (int i = 0; i < 4; ++i) {
        int row = rbase + i;
        int c   = ct * 16 + clane;
        D2lds[row * 64 + (c ^ ((row & 7) << 3))] = f2bf(w3v * gelu_grad_fast(a2acc[ctl][i]));
      }
    }

    // ---------------- noise + z pre-update (zacc <- 0.92 z + 0.4 n) --------
    // sched_barrier(0) between chunks: stop the scheduler from interleaving
    // 4 threefry bodies (R9: interleave -> register-pressure spike).
    {
      const uint32_t gs0 = (uint32_t)(wg * 64 + rbase) * 128u;
      #pragma unroll
      for (int tl = 0; tl < 4; ++tl) {
        N4 nz = noise4(fk0, fk1, gs0 + (uint32_t)((ch * 4 + tl) * 16 + clane));
        #pragma unroll
        for (int i = 0; i < 4; ++i) {
          float zv = zacc[tl][i];
          zacc[tl][i] = fmaf(0.4f, nz.v[i], fmaf(COEF, zv, zv));
        }
        __builtin_amdgcn_sched_barrier(0);
      }
    }

    // ---------------- backward: zacc += E @ (COEF*W1T) ----------------
    #pragma unroll 1
    for (int jb = 0; jb < 8; ++jb) {
      __syncthreads();   // D2 complete (jb=0) / HEu reads of jb-1 done
      bf16x8 d2a0 = lds_frag(D2lds, arow, 0  + ahi, 64);
      bf16x8 d2a1 = lds_frag(D2lds, arow, 32 + ahi, 64);
      #pragma unroll
      for (int ctl = 0; ctl < 2; ++ctl) {
        const int ct = ch * 2 + ctl;
        f32x4 eacc = f32x4{0.f, 0.f, 0.f, 0.f};
        eacc = MFMA16(d2a0, load_frag(W2Tp,      jb * 4 + ct, lane), eacc);
        eacc = MFMA16(d2a1, load_frag(W2Tp, 32 + jb * 4 + ct, lane), eacc);
        f32x4 a1acc = f32x4{0.f, 0.f, 0.f, 0.f};
        #pragma unroll
        for (int kb = 0; kb < 4; ++kb) {
          bf16x8 za = lds_frag(Zlds, arow, kb * 32 + ahi, 128);
          a1acc = MFMA16(za, load_frag(W1p, kb * 32 + jb * 4 + ct, lane), a1acc);
        }
        float bb = b1lds[jb * 64 + ct * 16 + clane];
        #pragma unroll
        for (int i = 0; i < 4; ++i) {
          int row = rbase + i;
          int c   = ct * 16 + clane;
          float ev = eacc[i] * gelu_grad_fast(a1acc[i] + bb);
          HEu[row * 64 + (c ^ ((row & 7) << 3))] = f2bf(ev);
        }
      }
      __syncthreads();   // E complete (both col-halves) before K-dim read
      #pragma unroll
      for (int kb = 0; kb < 2; ++kb) {
        bf16x8 ea = lds_frag(HEu, arow, kb * 32 + ahi, 64);
        #pragma unroll
        for (int tl = 0; tl < 4; ++tl)
          zacc[tl] = MFMA16(ea, load_frag(W1Tp, (jb * 2 + kb) * 8 + ch * 4 + tl, lane),
                            zacc[tl]);
      }
    }

    // ---------------- Zlds refresh with z_{t+1} ----------------
    // Safe: all Zlds reads of this step happened before the jb=7 mid-barrier.
    #pragma unroll
    for (int tl = 0; tl < 4; ++tl) {
      const int t = ch * 4 + tl;
      #pragma unroll
      for (int i = 0; i < 4; ++i) {
        int row = rbase + i;
        int col = t * 16 + clane;
        Zlds[row * 128 + (col ^ ((row & 7) << 3))] = f2bf(zacc[tl][i]);
      }
    }
    // next step's fwd jb=0 top barrier makes the refresh visible.
  }

  // ---- store ----
  #pragma unroll
  for (int tl = 0; tl < 4; ++tl) {
    const int t = ch * 4 + tl;
    #pragma unroll
    for (int i = 0; i < 4; ++i) {
      int row = rbase + i;
      out[(size_t)(wg * 64 + row) * ZDIM + t * 16 + clane] = zacc[tl][i];
    }
  }
}

// ===================== scalar fallback (round-3, verified) ==================
__global__ void transpose_w1(const float* __restrict__ W1, float* __restrict__ W1T) {
  int o = blockIdx.x * 256 + threadIdx.x;
  int j = o >> 7, k = o & 127;
  W1T[o] = W1[k * H1 + j];
}

__device__ __forceinline__ float normal_from_bits_exact(uint32_t bits) {
  float u01 = __uint_as_float((bits >> 9) | 0x3F800000u) - 1.0f;
  const float lo = -0.99999994f;
  float u = fmaxf(lo, u01 * 2.0f + lo);
  float w = -log1pf(-u * u);
  float p;
  if (w < 5.0f) {
    w -= 2.5f;
    p =             2.81022636e-08f;
    p = fmaf(p, w,  3.43273939e-07f);
    p = fmaf(p, w, -3.5233877e-06f);
    p = fmaf(p, w, -4.39150654e-06f);
    p = fmaf(p, w,  0.00021858087f);
    p = fmaf(p, w, -0.00125372503f);
    p = fmaf(p, w, -0.00417768164f);
    p = fmaf(p, w,  0.246640727f);
    p = fmaf(p, w,  1.50140941f);
  } else {
    w = sqrtf(w) - 3.0f;
    p =            -0.000200214257f;
    p = fmaf(p, w,  0.000100950558f);
    p = fmaf(p, w,  0.00134934322f);
    p = fmaf(p, w, -0.00367342844f);
    p = fmaf(p, w,  0.00573950773f);
    p = fmaf(p, w, -0.0076224613f);
    p = fmaf(p, w,  0.00943887047f);
    p = fmaf(p, w,  1.00167406f);
    p = fmaf(p, w,  2.83297682f);
  }
  return 1.41421356f * (p * u);
}

__global__ __launch_bounds__(256, 1) void langevin_scalar(
    const float* __restrict__ z0, const float* __restrict__ b1,
    const float* __restrict__ W2, const float* __restrict__ b2,
    const float* __restrict__ W3, const float* __restrict__ W1T,
    float* __restrict__ out)
{
  __shared__ float nbuf[256 * 33];
  const int tid = threadIdx.x;
  const uint32_t b = (uint32_t)blockIdx.x * 256u + (uint32_t)tid;
  float z[ZDIM];
  #pragma unroll
  for (int k = 0; k < ZDIM; ++k) z[k] = z0[(size_t)b * ZDIM + k];
  for (int step = 0; step < NSTEP; ++step) {
    uint32_t fk0, fk1;
    tf2x32(0u, 42u, 0u, (uint32_t)step, fk0, fk1);
    float acc2[H2];
    #pragma unroll
    for (int c = 0; c < H2; ++c) acc2[c] = b2[c];
    #pragma unroll 2
    for (int j = 0; j < H1; ++j) {
      const float* __restrict__ w = W1T + j * ZDIM;
      float s0 = 0.f, s1 = 0.f, s2 = 0.f, s3 = 0.f;
      #pragma unroll
      for (int k = 0; k < ZDIM; k += 4) {
        s0 = fmaf(z[k + 0], w[k + 0], s0); s1 = fmaf(z[k + 1], w[k + 1], s1);
        s2 = fmaf(z[k + 2], w[k + 2], s2); s3 = fmaf(z[k + 3], w[k + 3], s3);
      }
      float a1 = b1[j] + ((s0 + s1) + (s2 + s3));
      float h  = gelu_exact(a1);
      const float* __restrict__ w2r = W2 + j * H2;
      #pragma unroll
      for (int c = 0; c < H2; ++c) acc2[c] = fmaf(h, w2r[c], acc2[c]);
    }
    #pragma unroll
    for (int c = 0; c < H2; ++c) acc2[c] = W3[c] * gelu_grad_exact(acc2[c]);
    float g[ZDIM];
    #pragma unroll
    for (int k = 0; k < ZDIM; ++k) g[k] = 0.f;
    for (int j = 0; j < H1; ++j) {
      const float* __restrict__ w = W1T + j * ZDIM;
      float s0 = 0.f, s1 = 0.f, s2 = 0.f, s3 = 0.f;
      #pragma unroll
      for (int k = 0; k < ZDIM; k += 4) {
        s0 = fmaf(z[k + 0], w[k + 0], s0); s1 = fmaf(z[k + 1], w[k + 1], s1);
        s2 = fmaf(z[k + 2], w[k + 2], s2); s3 = fmaf(z[k + 3], w[k + 3], s3);
      }
      float a1 = b1[j] + ((s0 + s1) + (s2 + s3));
      const float* __restrict__ w2r = W2 + j * H2;
      float d0 = 0.f, d1 = 0.f, d2 = 0.f, d3 = 0.f;
      #pragma unroll
      for (int c = 0; c < H2; c += 4) {
        d0 = fmaf(acc2[c + 0], w2r[c + 0], d0); d1 = fmaf(acc2[c + 1], w2r[c + 1], d1);
        d2 = fmaf(acc2[c + 2], w2r[c + 2], d2); d3 = fmaf(acc2[c + 3], w2r[c + 3], d3);
      }
      float eps = ((d0 + d1) + (d2 + d3)) * gelu_grad_exact(a1);
      #pragma unroll
      for (int k = 0; k < ZDIM; ++k) g[k] = fmaf(eps, w[k], g[k]);
    }
    const uint32_t base = b * (uint32_t)ZDIM;
    #pragma unroll
    for (int kc = 0; kc < 4; ++kc) {
      for (int kk = 0; kk < 32; ++kk) {
        uint32_t f = base + (uint32_t)(kc * 32 + kk);
        uint32_t r0, r1;
        tf2x32(fk0, fk1, 0u, f, r0, r1);
        nbuf[tid * 33 + kk] = normal_from_bits_exact(r0 ^ r1);
      }
      #pragma unroll
      for (int i = 0; i < 32; ++i) {
        const int k = kc * 32 + i;
        z[k] += COEF * g[k] + COEF * z[k] + 0.4f * nbuf[tid * 33 + i];
      }
    }
  }
  #pragma unroll
  for (int k = 0; k < ZDIM; ++k) out[(size_t)b * ZDIM + k] = z[k];
}

// ------------------------------- launcher ----------------------------------
extern "C" void kernel_launch(void* const* d_in, const int* in_sizes, int n_in,
                              void* d_out, int out_size, void* d_ws, size_t ws_size,
                              hipStream_t stream) {
  (void)in_sizes; (void)n_in; (void)out_size;

  const float* z0 = (const float*)d_in[0];
  const float* W1 = (const float*)d_in[1];
  const float* b1 = (const float*)d_in[2];
  const float* W2 = (const float*)d_in[3];
  const float* b2 = (const float*)d_in[4];
  const float* W3 = (const float*)d_in[5];
  float* out = (float*)d_out;

  const size_t NEED = 196608u * 2u;   // 384 KB of packed bf16 tiles
  if (ws_size >= NEED) {
    unsigned short* W1p  = (unsigned short*)d_ws;
    unsigned short* W2p  = W1p  + 65536;
    unsigned short* W2Tp = W2p  + 32768;
    unsigned short* W1Tp = W2Tp + 32768;

    hipLaunchKernelGGL(pack_b, dim3(256), dim3(256), 0, stream, W1, W1p,  128, 512, 0, 65536, 1.0f);
    hipLaunchKernelGGL(pack_b, dim3(128), dim3(256), 0, stream, W2, W2p,  512,  64, 0, 32768, 1.0f);
    hipLaunchKernelGGL(pack_b, dim3(128), dim3(256), 0, stream, W2, W2Tp,  64, 512, 1, 32768, 1.0f);
    // W1Tp PRE-SCALED by COEF: bwd MFMAs accumulate COEF*G directly into zacc.
    hipLaunchKernelGGL(pack_b, dim3(256), dim3(256), 0, stream, W1, W1Tp, 512, 128, 1, 65536, COEF);
    hipLaunchKernelGGL(langevin_mfma, dim3(BATCH / 64), dim3(512), 0, stream,
                       z0, b1, b2, W3, W1p, W2p, W2Tp, W1Tp, out);
  } else {
    float* W1T = (float*)d_ws;
    hipLaunchKernelGGL(transpose_w1, dim3(256), dim3(256), 0, stream, W1, W1T);
    hipLaunchKernelGGL(langevin_scalar, dim3(BATCH / 256), dim3(256), 0, stream,
                       z0, b1, W2, b2, W3, W1T, out);
  }
}